// Round 10
// baseline (152.098 us; speedup 1.0000x reference)
//
#include <hip/hip_runtime.h>
#include <hip/hip_bf16.h>

#define EPSV 1e-5f
typedef __hip_bfloat16 bf16;
typedef __attribute__((ext_vector_type(8))) short v8s;
typedef __attribute__((ext_vector_type(4))) float v4f;
__device__ __forceinline__ float b2f(bf16 v) { return __bfloat162float(v); }
__device__ __forceinline__ bf16 f2b(float v) { return __float2bfloat16(v); }
__device__ __forceinline__ float bs2f(short s) {
  return __uint_as_float(((unsigned)(unsigned short)s) << 16);
}
__device__ __forceinline__ short f2bs(float v) {
  bf16 b = __float2bfloat16(v);
  return *(short*)&b;
}

__global__ __launch_bounds__(256) void fill_k(float* __restrict__ out, float val, int n)
{
  int i = blockIdx.x * 256 + threadIdx.x;
  if (i < n) out[i] = val;
}

// ---------- setup: zero cnt27; pack w2b/w3b [(s)*32+ic][oc]; Web flat; Wob [k][16] ----------
__global__ __launch_bounds__(256) void setup_k(
    const float* __restrict__ w2, const float* __restrict__ w3,
    const float* __restrict__ We, const float* __restrict__ Wo,
    bf16* __restrict__ w2b, bf16* __restrict__ w3b,
    bf16* __restrict__ Web, bf16* __restrict__ Wob, int* __restrict__ cnt27)
{
  int i = blockIdx.x * 256 + threadIdx.x;
  if (i < 64) cnt27[i] = 0;
  if (i < 9216) {
    int oc = i & 31, k = i >> 5, s = k >> 5, ic = k & 31;
    w2b[i] = f2b(w2[oc * 288 + ic * 9 + s]);
  } else if (i < 18432) {
    int j = i - 9216;
    int oc = j & 31, k = j >> 5, s = k >> 5, ic = k & 31;
    w3b[j] = f2b(w3[oc * 288 + ic * 9 + s]);
  } else if (i < 18432 + 49152) {
    Web[i - 18432] = f2b(We[i - 18432]);
  } else if (i < 18432 + 49152 + 2048) {
    int j = i - 18432 - 49152;               // j = k*16 + o
    int k = j >> 4, o = j & 15;
    Wob[j] = (o < 10) ? f2b(Wo[o * 128 + k]) : f2b(0.f);
  }
}

// ---------- compaction by 3-step expert signature (64 lists, all rows) ----------
__global__ __launch_bounds__(256) void compact27_k(
    const float* __restrict__ traj, int* __restrict__ cnt27, int* __restrict__ lists)
{
  int row = blockIdx.x * 256 + threadIdx.x;   // 32 blocks x 256 = 8192
  int t = threadIdx.x;
  __shared__ int lcnt[64], lbase[64];
  if (t < 64) lcnt[t] = 0;
  __syncthreads();
  int e[3];
#pragma unroll
  for (int s = 0; s < 3; ++s) {
    float4 tv = ((const float4*)traj)[s * 8192 + row];
    int ee = 0; float bv = tv.x;
    if (tv.y > bv) { bv = tv.y; ee = 1; }
    if (tv.z > bv) { bv = tv.z; ee = 2; }
    if (tv.w > bv) { bv = tv.w; ee = 3; }
    e[s] = ee;
  }
  int sig = e[0] + 4 * e[1] + 16 * e[2];
  int my = atomicAdd(&lcnt[sig], 1);
  __syncthreads();
  if (t < 64) lbase[t] = atomicAdd(&cnt27[t], lcnt[t]);
  __syncthreads();
  lists[sig * 8192 + lbase[sig] + my] = row;
}

// ---------- fused MoE 3 steps + head, state in wave-private LDS ----------
__global__ __launch_bounds__(256) void moe_fused_k(
    const float* __restrict__ hs, const bf16* __restrict__ Web,
    const float* __restrict__ be, const bf16* __restrict__ Wob,
    const float* __restrict__ bo, const float* __restrict__ sv,
    const int* __restrict__ cnt27, const int* __restrict__ lists,
    float* __restrict__ out)
{
  int t = threadIdx.x, lane = t & 63, wv = t >> 6;
  int m = lane & 15, kg = lane >> 4;
  __shared__ float st[4][16][132];            // per-wave state, +4 pad

  // find my tile: global wave id over prefix of ceil(cnt/16) (total <= 576 < 1024)
  int g = blockIdx.x * 4 + wv;
  int sig = -1, tile = 0, cntS = 0, base = 0;
  for (int s = 0; s < 64; ++s) {
    int c = cnt27[s], nt = (c + 15) >> 4;
    if (g >= base && g < base + nt) { sig = s; tile = g - base; cntS = c; }
    base += nt;
  }
  if (sig < 0) return;
  const int* lp = lists + sig * 8192;
  int ra = tile * 16 + m;
  int rowA = lp[ra < cntS ? ra : cntS - 1];

  // load 16 rows x 128 f32 into LDS
  const float* hrow = hs + rowA * 128 + kg * 32;
#pragma unroll
  for (int q = 0; q < 8; ++q)
    *(float4*)&st[wv][m][kg * 32 + q * 4] = ((const float4*)hrow)[q];

  int es[3] = { sig & 3, (sig >> 2) & 3, sig >> 4 };
#pragma unroll
  for (int stp = 0; stp < 3; ++stp) {
    int e = es[stp];
    if (e == 3) continue;
    const short* wbs = (const short*)(Web + e * 16384);
    v8s afr[4];
#pragma unroll
    for (int kk = 0; kk < 4; ++kk) {
      float4 a0 = *(const float4*)&st[wv][m][kk * 32 + kg * 8];
      float4 a1 = *(const float4*)&st[wv][m][kk * 32 + kg * 8 + 4];
      afr[kk][0] = f2bs(a0.x); afr[kk][1] = f2bs(a0.y);
      afr[kk][2] = f2bs(a0.z); afr[kk][3] = f2bs(a0.w);
      afr[kk][4] = f2bs(a1.x); afr[kk][5] = f2bs(a1.y);
      afr[kk][6] = f2bs(a1.z); afr[kk][7] = f2bs(a1.w);
    }
#pragma unroll
    for (int ob = 0; ob < 8; ++ob) {
      v4f acc = {0.f, 0.f, 0.f, 0.f};
#pragma unroll
      for (int kk = 0; kk < 4; ++kk) {
        v8s bfr;
#pragma unroll
        for (int j = 0; j < 8; ++j)
          bfr[j] = wbs[(kk * 32 + kg * 8 + j) * 128 + ob * 16 + m];
        acc = __builtin_amdgcn_mfma_f32_16x16x32_bf16(afr[kk], bfr, acc, 0, 0, 0);
      }
      float bb = be[e * 128 + ob * 16 + m];
#pragma unroll
      for (int j = 0; j < 4; ++j)
        st[wv][kg * 4 + j][ob * 16 + m] = fmaxf(acc[j] + bb, 0.f);
    }
  }

  // head: out[row][o] = state . Wo[o] + bo, * prod(sv)
  float ps = 1.f;
#pragma unroll
  for (int i = 0; i < 12; ++i) ps *= sv[i];
  const short* wos = (const short*)Wob;
  v8s afr[4];
#pragma unroll
  for (int kk = 0; kk < 4; ++kk) {
    float4 a0 = *(const float4*)&st[wv][m][kk * 32 + kg * 8];
    float4 a1 = *(const float4*)&st[wv][m][kk * 32 + kg * 8 + 4];
    afr[kk][0] = f2bs(a0.x); afr[kk][1] = f2bs(a0.y);
    afr[kk][2] = f2bs(a0.z); afr[kk][3] = f2bs(a0.w);
    afr[kk][4] = f2bs(a1.x); afr[kk][5] = f2bs(a1.y);
    afr[kk][6] = f2bs(a1.z); afr[kk][7] = f2bs(a1.w);
  }
  v4f acc = {0.f, 0.f, 0.f, 0.f};
#pragma unroll
  for (int kk = 0; kk < 4; ++kk) {
    v8s bfr;
#pragma unroll
    for (int j = 0; j < 8; ++j)
      bfr[j] = wos[(kk * 32 + kg * 8 + j) * 16 + m];
    acc = __builtin_amdgcn_mfma_f32_16x16x32_bf16(afr[kk], bfr, acc, 0, 0, 0);
  }
  if (m < 10) {
    float bov = bo[m];
#pragma unroll
    for (int j = 0; j < 4; ++j) {
      int idx = tile * 16 + kg * 4 + j;
      if (idx < cntS) out[lp[idx] * 10 + m] = (acc[j] + bov) * ps;
    }
  }
}

// ---------- conv1 stats via autocorrelation: 4 images/block -> 54 partials ----------
__global__ __launch_bounds__(256) void conv1_acc_k(
    const float* __restrict__ x, float* __restrict__ partial)
{
  int t = threadIdx.x;
  __shared__ __align__(16) float xs[1024];
  float M[45], S[9];
#pragma unroll
  for (int k = 0; k < 45; ++k) M[k] = 0.f;
#pragma unroll
  for (int k = 0; k < 9; ++k) S[k] = 0.f;
  for (int im = 0; im < 4; ++im) {
    int img = blockIdx.x * 4 + im;
    ((float4*)xs)[t] = ((const float4*)(x + img * 1024))[t];
    __syncthreads();
    for (int p = t; p < 900; p += 256) {
      int y = p / 30, xx = p - y * 30;
      const float* r0 = xs + y * 32 + xx;
      float v[9];
      v[0] = r0[0];  v[1] = r0[1];  v[2] = r0[2];
      v[3] = r0[32]; v[4] = r0[33]; v[5] = r0[34];
      v[6] = r0[64]; v[7] = r0[65]; v[8] = r0[66];
      int idx = 0;
#pragma unroll
      for (int i = 0; i < 9; ++i) {
        S[i] += v[i];
#pragma unroll
        for (int j = i; j < 9; ++j) M[idx++] = fmaf(v[i], v[j], M[idx]);
      }
    }
    __syncthreads();
  }
  float a[54];
#pragma unroll
  for (int k = 0; k < 45; ++k) a[k] = M[k];
#pragma unroll
  for (int k = 0; k < 9; ++k) a[45 + k] = S[k];
#pragma unroll
  for (int k = 0; k < 54; ++k) {
#pragma unroll
    for (int off = 32; off; off >>= 1) a[k] += __shfl_down(a[k], off, 64);
  }
  __shared__ float red[4][54];
  int wv = t >> 6, lane = t & 63;
  if (lane == 0) {
#pragma unroll
    for (int k = 0; k < 54; ++k) red[wv][k] = a[k];
  }
  __syncthreads();
  if (t < 54)
    partial[blockIdx.x * 64 + t] = red[0][t] + red[1][t] + red[2][t] + red[3][t];
}

// ---------- fused: reduce 512x54 partials + conv1 BN params (1 block) ----------
__global__ __launch_bounds__(256) void bn1_fused_k(
    const float* __restrict__ partial, const float* __restrict__ w1,
    const float* __restrict__ b1, const float* __restrict__ g,
    const float* __restrict__ bt, float* __restrict__ bnp)
{
  int t = threadIdx.x, c = t & 63, half = t >> 6;
  float s = 0.f;
  for (int i = half; i < 512; i += 4) s += partial[i * 64 + c];
  __shared__ float red[4][64];
  red[half][c] = s;
  __syncthreads();
  __shared__ float Ms[54];
  if (t < 54) Ms[t] = red[0][t] + red[1][t] + red[2][t] + red[3][t];
  __syncthreads();
  if (t < 32) {
    float w[9];
#pragma unroll
    for (int j = 0; j < 9; ++j) w[j] = w1[t * 9 + j];
    float b = b1[t];
    float wS = 0.f;
#pragma unroll
    for (int i = 0; i < 9; ++i) wS = fmaf(w[i], Ms[45 + i], wS);
    float wMw = 0.f;
    int idx = 0;
#pragma unroll
    for (int i = 0; i < 9; ++i)
#pragma unroll
      for (int j = i; j < 9; ++j) {
        float coef = (i == j) ? 1.f : 2.f;
        wMw = fmaf(coef * w[i] * w[j], Ms[idx++], wMw);
      }
    const float Np = 2048.f * 900.f;
    float mean = (wS + Np * b) / Np;
    float sumsq = wMw + 2.f * b * wS + Np * b * b;
    float var = sumsq / Np - mean * mean;
    float sc = g[t] / sqrtf(var + EPSV);
    bnp[2 * t] = sc;
    bnp[2 * t + 1] = bt[t] - mean * sc;
  }
}

// ---------- conv1 apply: block per image, float2 patch loads, regs for weights ----------
__global__ __launch_bounds__(256) void conv1_apply_k(
    const float* __restrict__ x, const float* __restrict__ w1,
    const float* __restrict__ b1, const float* __restrict__ bnp,
    bf16* __restrict__ pooled1)
{
  int img = blockIdx.x, t = threadIdx.x;
  __shared__ __align__(16) float xs[1024];
  ((float4*)xs)[t] = ((const float4*)(x + img * 1024))[t];
  __syncthreads();
  int c = t & 31;
  float w[9];
#pragma unroll
  for (int j = 0; j < 9; ++j) w[j] = w1[c * 9 + j];
  float bias = b1[c], sc = bnp[2 * c], sh = bnp[2 * c + 1];
  bf16* outp = pooled1 + img * 7200;
  for (int idx = t; idx < 7200; idx += 256) {
    int pp = idx >> 5;
    int py = pp / 15, px = pp - py * 15;
    int y0 = 2 * py, x0 = 2 * px;
    float rv[4][4];
#pragma unroll
    for (int rr = 0; rr < 4; ++rr) {
      float2 lo = *(const float2*)(xs + (y0 + rr) * 32 + x0);
      float2 hi = *(const float2*)(xs + (y0 + rr) * 32 + x0 + 2);
      rv[rr][0] = lo.x; rv[rr][1] = lo.y; rv[rr][2] = hi.x; rv[rr][3] = hi.y;
    }
    float r = 0.f;
#pragma unroll
    for (int i = 0; i < 2; ++i)
#pragma unroll
      for (int j = 0; j < 2; ++j) {
        float v = bias;
        v = fmaf(rv[i][j],     w[0], v); v = fmaf(rv[i][j + 1],     w[1], v); v = fmaf(rv[i][j + 2],     w[2], v);
        v = fmaf(rv[i + 1][j], w[3], v); v = fmaf(rv[i + 1][j + 1], w[4], v); v = fmaf(rv[i + 1][j + 2], w[5], v);
        v = fmaf(rv[i + 2][j], w[6], v); v = fmaf(rv[i + 2][j + 1], w[7], v); v = fmaf(rv[i + 2][j + 2], w[8], v);
        r += fmaxf(fmaf(v, sc, sh), 0.f);
      }
    outp[idx] = f2b(r * 0.25f);
  }
}

// ---------- generic partial reduce -> scale/shift (conv2/conv3 stats) ----------
__global__ __launch_bounds__(256) void bn_reduce_partial_k(
    const float* __restrict__ partial, const float* __restrict__ g,
    const float* __restrict__ bt, float* __restrict__ bnp,
    int nimg, float invn)
{
  int c = blockIdx.x, t = threadIdx.x;
  float s = 0.f, ss = 0.f;
  for (int i = t; i < nimg; i += 256) {
    s += partial[i * 64 + c * 2];
    ss += partial[i * 64 + c * 2 + 1];
  }
#pragma unroll
  for (int off = 32; off; off >>= 1) { s += __shfl_down(s, off, 64); ss += __shfl_down(ss, off, 64); }
  __shared__ float rs[4], rss[4];
  int wv = t >> 6, lane = t & 63;
  if (lane == 0) { rs[wv] = s; rss[wv] = ss; }
  __syncthreads();
  if (t == 0) {
    s = rs[0] + rs[1] + rs[2] + rs[3];
    ss = rss[0] + rss[1] + rss[2] + rss[3];
    float mean = s * invn;
    float var = ss * invn - mean * mean;
    float sc = g[c] / sqrtf(var + EPSV);
    bnp[2 * c] = sc;
    bnp[2 * c + 1] = bt[c] - mean * sc;
  }
}

// ---------- implicit-GEMM conv via MFMA, NHWC in/out, fused BN-stats partials ----------
template <int IN_W, int OUT_W, int OUT_PIX, bool OUT_BF16>
__global__ __launch_bounds__(256) void conv_mfma_k(
    const bf16* __restrict__ in, const bf16* __restrict__ wb,
    void* __restrict__ outv, float* __restrict__ partial, int ntiles)
{
  constexpr int IN_PIX = IN_W * IN_W;
  int t = threadIdx.x, lane = t & 63;
  int m = lane & 15, kg = lane >> 4;
  const short* wbs = (const short*)wb;
  v8s bfr[9][2];
#pragma unroll
  for (int s = 0; s < 9; ++s)
#pragma unroll
    for (int ob = 0; ob < 2; ++ob)
#pragma unroll
      for (int j = 0; j < 8; ++j)
        bfr[s][ob][j] = wbs[(s * 32 + kg * 8 + j) * 32 + ob * 16 + m];

  float rs0 = 0.f, rss0 = 0.f, rs1 = 0.f, rss1 = 0.f;
  int gwave = blockIdx.x * 4 + (t >> 6);
  int nw = gridDim.x * 4;
  for (int tile = gwave; tile < ntiles; tile += nw) {
    unsigned p = tile * 16 + m;
    unsigned img = p / OUT_PIX, pix = p - img * OUT_PIX;
    unsigned y = pix / OUT_W, x = pix - y * OUT_W;
    const bf16* ap = in + img * (IN_PIX * 32) + (y * IN_W + x) * 32 + kg * 8;
    v4f acc0 = {0.f, 0.f, 0.f, 0.f}, acc1 = {0.f, 0.f, 0.f, 0.f};
#pragma unroll
    for (int ky = 0; ky < 3; ++ky)
#pragma unroll
      for (int kx = 0; kx < 3; ++kx) {
        v8s a = *(const v8s*)(ap + (ky * IN_W + kx) * 32);
        acc0 = __builtin_amdgcn_mfma_f32_16x16x32_bf16(a, bfr[ky * 3 + kx][0], acc0, 0, 0, 0);
        acc1 = __builtin_amdgcn_mfma_f32_16x16x32_bf16(a, bfr[ky * 3 + kx][1], acc1, 0, 0, 0);
      }
#pragma unroll
    for (int j = 0; j < 4; ++j) {
      rs0 += acc0[j]; rss0 = fmaf(acc0[j], acc0[j], rss0);
      rs1 += acc1[j]; rss1 = fmaf(acc1[j], acc1[j], rss1);
      unsigned pr = tile * 16 + kg * 4 + j;
      unsigned img2 = pr / OUT_PIX, pix2 = pr - img2 * OUT_PIX;
      unsigned base = (img2 * OUT_PIX + pix2) * 32;
      if (OUT_BF16) {
        bf16* o = (bf16*)outv;
        o[base + m] = f2b(acc0[j]);
        o[base + 16 + m] = f2b(acc1[j]);
      } else {
        float* o = (float*)outv;
        o[base + m] = acc0[j];
        o[base + 16 + m] = acc1[j];
      }
    }
  }
  rs0 += __shfl_xor(rs0, 16, 64);  rs0 += __shfl_xor(rs0, 32, 64);
  rss0 += __shfl_xor(rss0, 16, 64); rss0 += __shfl_xor(rss0, 32, 64);
  rs1 += __shfl_xor(rs1, 16, 64);  rs1 += __shfl_xor(rs1, 32, 64);
  rss1 += __shfl_xor(rss1, 16, 64); rss1 += __shfl_xor(rss1, 32, 64);
  __shared__ float red[4][32][2];
  int wv = t >> 6;
  if (lane < 16) {
    red[wv][lane][0] = rs0;      red[wv][lane][1] = rss0;
    red[wv][16 + lane][0] = rs1; red[wv][16 + lane][1] = rss1;
  }
  __syncthreads();
  if (t < 64) {
    int cc = t >> 1, j = t & 1;
    partial[blockIdx.x * 64 + t] = red[0][cc][j] + red[1][cc][j] + red[2][cc][j] + red[3][cc][j];
  }
}

// ---------- conv2 apply: NHWC vectorized BN+ReLU+pool 13->6 -> NHWC bf16 ----------
__global__ __launch_bounds__(256) void conv2_apply_k(
    const bf16* __restrict__ in, const float* __restrict__ bnp,
    bf16* __restrict__ out)
{
  int idx = blockIdx.x * 256 + threadIdx.x;  // exactly 2048*36*4
  int img = idx / 144, r = idx - img * 144;
  int pp = r >> 2, c8 = r & 3;
  int py = pp / 6, px = pp - py * 6;
  int ip0 = (2 * py) * 13 + 2 * px;
  const bf16* bp = in + (img * 169 + ip0) * 32 + c8 * 8;
  v8s a = *(const v8s*)bp;
  v8s b = *(const v8s*)(bp + 32);
  v8s cc = *(const v8s*)(bp + 13 * 32);
  v8s d = *(const v8s*)(bp + 14 * 32);
  const float* bn = bnp + c8 * 16;
  union { v8s v; short s[8]; bf16 h[8]; } res;
#pragma unroll
  for (int k = 0; k < 8; ++k) {
    float sc = bn[2 * k], sh = bn[2 * k + 1];
    float v = fmaxf(fmaf(bs2f(a[k]), sc, sh), 0.f) + fmaxf(fmaf(bs2f(b[k]), sc, sh), 0.f)
            + fmaxf(fmaf(bs2f(cc[k]), sc, sh), 0.f) + fmaxf(fmaf(bs2f(d[k]), sc, sh), 0.f);
    res.h[k] = f2b(v * 0.25f);
  }
  *(v8s*)(out + (img * 36 + pp) * 32 + c8 * 8) = res.v;
}

// ---------- conv3 apply + pool + broadcast to 4 beams (NHWC fp32 in) ----------
__global__ __launch_bounds__(256) void conv3_apply_k(
    const float* __restrict__ in, const float* __restrict__ bnp,
    float* __restrict__ hs)
{
  int idx = blockIdx.x * 256 + threadIdx.x;  // exactly 2048*128
  int img = idx >> 7, r = idx & 127;
  int c = r >> 2, q = r & 3;
  int py = q >> 1, px = q & 1;
  int p0 = py * 8 + px * 2;
  const float* bp = in + img * 512 + c;
  float sc = bnp[2 * c], sh = bnp[2 * c + 1];
  float v = (fmaxf(fmaf(bp[p0 * 32], sc, sh), 0.f)
           + fmaxf(fmaf(bp[(p0 + 1) * 32], sc, sh), 0.f)
           + fmaxf(fmaf(bp[(p0 + 4) * 32], sc, sh), 0.f)
           + fmaxf(fmaf(bp[(p0 + 5) * 32], sc, sh), 0.f)) * 0.25f;
  float* hb = hs + img * 512 + r;
  hb[0] = v; hb[128] = v; hb[256] = v; hb[384] = v;
}

extern "C" void kernel_launch(void* const* d_in, const int* in_sizes, int n_in,
                              void* d_out, int out_size, void* d_ws, size_t ws_size,
                              hipStream_t stream)
{
  float* out = (float*)d_out;

  static const int EXP[19] = {2097152, 98304, 12, 288, 32, 9216, 32, 9216, 32,
                              32, 32, 32, 32, 32, 32, 49152, 384, 1280, 10};
  int bad = -1;
  if (n_in != 19) bad = 100;
  else
    for (int i = 0; i < 19; ++i)
      if (in_sizes[i] != EXP[i]) { bad = i; break; }
  if (bad >= 0) {
    fill_k<<<(out_size + 255) / 256, 256, 0, stream>>>(out, 1000.f + 10.f * bad, out_size);
    return;
  }
  const size_t NEED = 75764992;
  if (ws_size < NEED) {
    fill_k<<<(out_size + 255) / 256, 256, 0, stream>>>(
        out, 3000.f + (float)(ws_size >> 20), out_size);
    return;
  }

  const float* x    = (const float*)d_in[0];
  const float* traj = (const float*)d_in[1];
  const float* sv   = (const float*)d_in[2];
  const float* c1w  = (const float*)d_in[3];
  const float* c1b  = (const float*)d_in[4];
  const float* c2w  = (const float*)d_in[5];
  const float* c3w  = (const float*)d_in[7];
  const float* g1   = (const float*)d_in[9];
  const float* bt1  = (const float*)d_in[10];
  const float* g2   = (const float*)d_in[11];
  const float* bt2  = (const float*)d_in[12];
  const float* g3   = (const float*)d_in[13];
  const float* bt3  = (const float*)d_in[14];
  const float* We   = (const float*)d_in[15];
  const float* be   = (const float*)d_in[16];
  const float* Wo   = (const float*)d_in[17];
  const float* bo   = (const float*)d_in[18];

  char* w = (char*)d_ws;
  bf16*  pooled1  = (bf16*)(w + 0);          // NHWC bf16, 29,491,200 B
  bf16*  conv2out = (bf16*)(w + 29491200);   // NHWC bf16, 22,151,168 B
  bf16*  pooled2  = (bf16*)(w + 51642368);   // NHWC bf16, 4,718,592 B
  bf16*  Web      = (bf16*)(w + 56360960);   // 98,304 B
  float* conv3out = (float*)(w + 61079552);  // NHWC f32, 4,194,304 B
  float* hsA      = (float*)(w + 65273856);  // 4,194,304 B
  float* hsB      = (float*)(w + 69468160);  // 4,194,304 B (weight staging only)
  float* bnp1     = (float*)(w + 73662464);
  float* bnp2     = (float*)(w + 73662720);
  float* bnp3     = (float*)(w + 73662976);
  int*   cnt27    = (int*)(w + 73663488);    // 256 B
  bf16*  Wob      = (bf16*)(w + 73663744);   // 4,096 B
  int*   lists    = (int*)(w + 73667840);    // 64*8192*4 = 2,097,152 -> end 75,764,992
  // short-lived aliases (lifetimes verified disjoint):
  float* partial1 = (float*)conv2out;        // dead before conv2 mfma writes
  float* partial2 = (float*)pooled2;         // dead before conv2_apply writes
  float* partial3 = (float*)hsA;             // dead before conv3_apply writes
  bf16*  w2b      = (bf16*)hsB;
  bf16*  w3b      = w2b + 9216;

  setup_k<<<272, 256, 0, stream>>>(c2w, c3w, We, Wo, w2b, w3b, Web, Wob, cnt27);
  compact27_k<<<32, 256, 0, stream>>>(traj, cnt27, lists);
  conv1_acc_k<<<512, 256, 0, stream>>>(x, partial1);
  bn1_fused_k<<<1, 256, 0, stream>>>(partial1, c1w, c1b, g1, bt1, bnp1);
  conv1_apply_k<<<2048, 256, 0, stream>>>(x, c1w, c1b, bnp1, pooled1);
  conv_mfma_k<15, 13, 169, true><<<1024, 256, 0, stream>>>(pooled1, w2b, conv2out,
                                                           partial2, 21632);
  bn_reduce_partial_k<<<32, 256, 0, stream>>>(partial2, g2, bt2, bnp2, 1024,
                                              1.f / (2048.f * 169.f));
  conv2_apply_k<<<1152, 256, 0, stream>>>(conv2out, bnp2, pooled2);
  conv_mfma_k<6, 4, 16, false><<<256, 256, 0, stream>>>(pooled2, w3b, conv3out,
                                                        partial3, 2048);
  bn_reduce_partial_k<<<32, 256, 0, stream>>>(partial3, g3, bt3, bnp3, 256,
                                              1.f / (2048.f * 16.f));
  conv3_apply_k<<<1024, 256, 0, stream>>>(conv3out, bnp3, hsA);
  moe_fused_k<<<256, 256, 0, stream>>>(hsA, Web, be, Wob, bo, sv, cnt27, lists, out);
}

// Round 11
// 142.149 us; speedup vs baseline: 1.0700x; 1.0700x over previous
//
#include <hip/hip_runtime.h>
#include <hip/hip_bf16.h>

#define EPSV 1e-5f
typedef __hip_bfloat16 bf16;
typedef __attribute__((ext_vector_type(8))) short v8s;
typedef __attribute__((ext_vector_type(4))) float v4f;
__device__ __forceinline__ float b2f(bf16 v) { return __bfloat162float(v); }
__device__ __forceinline__ bf16 f2b(float v) { return __float2bfloat16(v); }
__device__ __forceinline__ float bs2f(short s) {
  return __uint_as_float(((unsigned)(unsigned short)s) << 16);
}
__device__ __forceinline__ short f2bs(float v) {
  bf16 b = __float2bfloat16(v);
  return *(short*)&b;
}

__global__ __launch_bounds__(256) void fill_k(float* __restrict__ out, float val, int n)
{
  int i = blockIdx.x * 256 + threadIdx.x;
  if (i < n) out[i] = val;
}

// ---------- setup: zero accumulators/cnt; pack w2b/w3b [(s)*32+ic][oc]; Web; Wob ----------
__global__ __launch_bounds__(256) void setup_k(
    const float* __restrict__ w2, const float* __restrict__ w3,
    const float* __restrict__ We, const float* __restrict__ Wo,
    bf16* __restrict__ w2b, bf16* __restrict__ w3b,
    bf16* __restrict__ Web, bf16* __restrict__ Wob,
    int* __restrict__ cnt27, float* __restrict__ Macc,
    float* __restrict__ Sacc2, float* __restrict__ Sacc3)
{
  int i = blockIdx.x * 256 + threadIdx.x;
  if (i < 64) {
    cnt27[i] = 0;
    Macc[i] = 0.f;
    Sacc2[i] = 0.f;
    Sacc3[i] = 0.f;
  }
  if (i < 9216) {
    int oc = i & 31, k = i >> 5, s = k >> 5, ic = k & 31;
    w2b[i] = f2b(w2[oc * 288 + ic * 9 + s]);
  } else if (i < 18432) {
    int j = i - 9216;
    int oc = j & 31, k = j >> 5, s = k >> 5, ic = k & 31;
    w3b[j] = f2b(w3[oc * 288 + ic * 9 + s]);
  } else if (i < 18432 + 49152) {
    Web[i - 18432] = f2b(We[i - 18432]);
  } else if (i < 18432 + 49152 + 2048) {
    int j = i - 18432 - 49152;               // j = k*16 + o
    int k = j >> 4, o = j & 15;
    Wob[j] = (o < 10) ? f2b(Wo[o * 128 + k]) : f2b(0.f);
  }
}

// ---------- front: blocks 0-31 = signature compaction; 32-543 = conv1 autocorr ----------
__global__ __launch_bounds__(256) void front_k(
    const float* __restrict__ traj, const float* __restrict__ x,
    int* __restrict__ cnt27, int* __restrict__ lists, float* __restrict__ Macc)
{
  int t = threadIdx.x;
  if (blockIdx.x < 32) {
    int row = blockIdx.x * 256 + t;
    __shared__ int lcnt[64], lbase[64];
    if (t < 64) lcnt[t] = 0;
    __syncthreads();
    int e[3];
#pragma unroll
    for (int s = 0; s < 3; ++s) {
      float4 tv = ((const float4*)traj)[s * 8192 + row];
      int ee = 0; float bv = tv.x;
      if (tv.y > bv) { bv = tv.y; ee = 1; }
      if (tv.z > bv) { bv = tv.z; ee = 2; }
      if (tv.w > bv) { bv = tv.w; ee = 3; }
      e[s] = ee;
    }
    int sig = e[0] + 4 * e[1] + 16 * e[2];
    int my = atomicAdd(&lcnt[sig], 1);
    __syncthreads();
    if (t < 64) lbase[t] = atomicAdd(&cnt27[t], lcnt[t]);
    __syncthreads();
    lists[sig * 8192 + lbase[sig] + my] = row;
    return;
  }
  // conv1 autocorrelation: 4 images per block
  int blk = blockIdx.x - 32;
  __shared__ __align__(16) float xs[1024];
  float M[45], S[9];
#pragma unroll
  for (int k = 0; k < 45; ++k) M[k] = 0.f;
#pragma unroll
  for (int k = 0; k < 9; ++k) S[k] = 0.f;
  for (int im = 0; im < 4; ++im) {
    int img = blk * 4 + im;
    ((float4*)xs)[t] = ((const float4*)(x + img * 1024))[t];
    __syncthreads();
    for (int p = t; p < 900; p += 256) {
      int y = p / 30, xx = p - y * 30;
      const float* r0 = xs + y * 32 + xx;
      float v[9];
      v[0] = r0[0];  v[1] = r0[1];  v[2] = r0[2];
      v[3] = r0[32]; v[4] = r0[33]; v[5] = r0[34];
      v[6] = r0[64]; v[7] = r0[65]; v[8] = r0[66];
      int idx = 0;
#pragma unroll
      for (int i = 0; i < 9; ++i) {
        S[i] += v[i];
#pragma unroll
        for (int j = i; j < 9; ++j) M[idx++] = fmaf(v[i], v[j], M[idx]);
      }
    }
    __syncthreads();
  }
  float a[54];
#pragma unroll
  for (int k = 0; k < 45; ++k) a[k] = M[k];
#pragma unroll
  for (int k = 0; k < 9; ++k) a[45 + k] = S[k];
#pragma unroll
  for (int k = 0; k < 54; ++k) {
#pragma unroll
    for (int off = 32; off; off >>= 1) a[k] += __shfl_down(a[k], off, 64);
  }
  __shared__ float red[4][54];
  int wv = t >> 6, lane = t & 63;
  if (lane == 0) {
#pragma unroll
    for (int k = 0; k < 54; ++k) red[wv][k] = a[k];
  }
  __syncthreads();
  if (t < 54)
    atomicAdd(&Macc[t], red[0][t] + red[1][t] + red[2][t] + red[3][t]);
}

// ---------- conv1 apply: inline BN params from autocorr sums ----------
__global__ __launch_bounds__(256) void conv1_apply_k(
    const float* __restrict__ x, const float* __restrict__ w1,
    const float* __restrict__ b1, const float* __restrict__ g,
    const float* __restrict__ bt, const float* __restrict__ Macc,
    bf16* __restrict__ pooled1)
{
  int img = blockIdx.x, t = threadIdx.x;
  __shared__ __align__(16) float xs[1024];
  ((float4*)xs)[t] = ((const float4*)(x + img * 1024))[t];
  __syncthreads();
  int c = t & 31;
  float w[9];
#pragma unroll
  for (int j = 0; j < 9; ++j) w[j] = w1[c * 9 + j];
  float bias = b1[c];
  // inline bnp1 from Macc (wave-uniform loads, per-thread channel math)
  float wS = 0.f;
#pragma unroll
  for (int i = 0; i < 9; ++i) wS = fmaf(w[i], Macc[45 + i], wS);
  float wMw = 0.f;
  {
    int idx = 0;
#pragma unroll
    for (int i = 0; i < 9; ++i)
#pragma unroll
      for (int j = i; j < 9; ++j) {
        float coef = (i == j) ? 1.f : 2.f;
        wMw = fmaf(coef * w[i] * w[j], Macc[idx], wMw);
        ++idx;
      }
  }
  const float Np = 2048.f * 900.f;
  float mean = (wS + Np * bias) / Np;
  float sumsq = wMw + 2.f * bias * wS + Np * bias * bias;
  float var = sumsq / Np - mean * mean;
  float sc = g[c] / sqrtf(var + EPSV);
  float sh = bt[c] - mean * sc;

  bf16* outp = pooled1 + img * 7200;
  for (int idx = t; idx < 7200; idx += 256) {
    int pp = idx >> 5;
    int py = pp / 15, px = pp - py * 15;
    int y0 = 2 * py, x0 = 2 * px;
    float rv[4][4];
#pragma unroll
    for (int rr = 0; rr < 4; ++rr) {
      float2 lo = *(const float2*)(xs + (y0 + rr) * 32 + x0);
      float2 hi = *(const float2*)(xs + (y0 + rr) * 32 + x0 + 2);
      rv[rr][0] = lo.x; rv[rr][1] = lo.y; rv[rr][2] = hi.x; rv[rr][3] = hi.y;
    }
    float r = 0.f;
#pragma unroll
    for (int i = 0; i < 2; ++i)
#pragma unroll
      for (int j = 0; j < 2; ++j) {
        float v = bias;
        v = fmaf(rv[i][j],     w[0], v); v = fmaf(rv[i][j + 1],     w[1], v); v = fmaf(rv[i][j + 2],     w[2], v);
        v = fmaf(rv[i + 1][j], w[3], v); v = fmaf(rv[i + 1][j + 1], w[4], v); v = fmaf(rv[i + 1][j + 2], w[5], v);
        v = fmaf(rv[i + 2][j], w[6], v); v = fmaf(rv[i + 2][j + 1], w[7], v); v = fmaf(rv[i + 2][j + 2], w[8], v);
        r += fmaxf(fmaf(v, sc, sh), 0.f);
      }
    outp[idx] = f2b(r * 0.25f);
  }
}

// ---------- implicit-GEMM conv via MFMA, NHWC in/out, atomic BN-stats ----------
template <int IN_W, int OUT_W, int OUT_PIX, bool OUT_BF16>
__global__ __launch_bounds__(256) void conv_mfma_k(
    const bf16* __restrict__ in, const bf16* __restrict__ wb,
    void* __restrict__ outv, float* __restrict__ sacc, int ntiles)
{
  constexpr int IN_PIX = IN_W * IN_W;
  int t = threadIdx.x, lane = t & 63;
  int m = lane & 15, kg = lane >> 4;
  const short* wbs = (const short*)wb;
  v8s bfr[9][2];
#pragma unroll
  for (int s = 0; s < 9; ++s)
#pragma unroll
    for (int ob = 0; ob < 2; ++ob)
#pragma unroll
      for (int j = 0; j < 8; ++j)
        bfr[s][ob][j] = wbs[(s * 32 + kg * 8 + j) * 32 + ob * 16 + m];

  float rs0 = 0.f, rss0 = 0.f, rs1 = 0.f, rss1 = 0.f;
  int gwave = blockIdx.x * 4 + (t >> 6);
  int nw = gridDim.x * 4;
  for (int tile = gwave; tile < ntiles; tile += nw) {
    unsigned p = tile * 16 + m;
    unsigned img = p / OUT_PIX, pix = p - img * OUT_PIX;
    unsigned y = pix / OUT_W, x = pix - y * OUT_W;
    const bf16* ap = in + img * (IN_PIX * 32) + (y * IN_W + x) * 32 + kg * 8;
    v4f acc0 = {0.f, 0.f, 0.f, 0.f}, acc1 = {0.f, 0.f, 0.f, 0.f};
#pragma unroll
    for (int ky = 0; ky < 3; ++ky)
#pragma unroll
      for (int kx = 0; kx < 3; ++kx) {
        v8s a = *(const v8s*)(ap + (ky * IN_W + kx) * 32);
        acc0 = __builtin_amdgcn_mfma_f32_16x16x32_bf16(a, bfr[ky * 3 + kx][0], acc0, 0, 0, 0);
        acc1 = __builtin_amdgcn_mfma_f32_16x16x32_bf16(a, bfr[ky * 3 + kx][1], acc1, 0, 0, 0);
      }
#pragma unroll
    for (int j = 0; j < 4; ++j) {
      rs0 += acc0[j]; rss0 = fmaf(acc0[j], acc0[j], rss0);
      rs1 += acc1[j]; rss1 = fmaf(acc1[j], acc1[j], rss1);
      unsigned pr = tile * 16 + kg * 4 + j;
      unsigned img2 = pr / OUT_PIX, pix2 = pr - img2 * OUT_PIX;
      unsigned base = (img2 * OUT_PIX + pix2) * 32;
      if (OUT_BF16) {
        bf16* o = (bf16*)outv;
        o[base + m] = f2b(acc0[j]);
        o[base + 16 + m] = f2b(acc1[j]);
      } else {
        float* o = (float*)outv;
        o[base + m] = acc0[j];
        o[base + 16 + m] = acc1[j];
      }
    }
  }
  rs0 += __shfl_xor(rs0, 16, 64);  rss0 += __shfl_xor(rss0, 16, 64);
  rs0 += __shfl_xor(rs0, 32, 64);  rss0 += __shfl_xor(rss0, 32, 64);
  rs1 += __shfl_xor(rs1, 16, 64);  rss1 += __shfl_xor(rss1, 16, 64);
  rs1 += __shfl_xor(rs1, 32, 64);  rss1 += __shfl_xor(rss1, 32, 64);
  __shared__ float red[4][32][2];
  int wv = t >> 6;
  if (lane < 16) {
    red[wv][lane][0] = rs0;      red[wv][lane][1] = rss0;
    red[wv][16 + lane][0] = rs1; red[wv][16 + lane][1] = rss1;
  }
  __syncthreads();
  if (t < 64) {
    int cc = t >> 1, j = t & 1;
    atomicAdd(&sacc[t], red[0][cc][j] + red[1][cc][j] + red[2][cc][j] + red[3][cc][j]);
  }
}

// ---------- conv2 apply: inline bnp2 from Sacc2; BN+ReLU+pool -> NHWC bf16 ----------
__global__ __launch_bounds__(256) void conv2_apply_k(
    const bf16* __restrict__ in, const float* __restrict__ Sacc2,
    const float* __restrict__ g, const float* __restrict__ bt,
    bf16* __restrict__ out)
{
  int idx = blockIdx.x * 256 + threadIdx.x;  // exactly 2048*36*4
  int img = idx / 144, r = idx - img * 144;
  int pp = r >> 2, c8 = r & 3;
  int py = pp / 6, px = pp - py * 6;
  int ip0 = (2 * py) * 13 + 2 * px;
  const bf16* bp = in + (img * 169 + ip0) * 32 + c8 * 8;
  v8s a = *(const v8s*)bp;
  v8s b = *(const v8s*)(bp + 32);
  v8s cc = *(const v8s*)(bp + 13 * 32);
  v8s d = *(const v8s*)(bp + 14 * 32);
  const float invn = 1.f / (2048.f * 169.f);
  union { v8s v; short s[8]; bf16 h[8]; } res;
#pragma unroll
  for (int k = 0; k < 8; ++k) {
    int ch = c8 * 8 + k;
    float s = Sacc2[2 * ch], ssum = Sacc2[2 * ch + 1];
    float mean = s * invn;
    float var = ssum * invn - mean * mean;
    float sc = g[ch] / sqrtf(var + EPSV);
    float sh = bt[ch] - mean * sc;
    float v = fmaxf(fmaf(bs2f(a[k]), sc, sh), 0.f) + fmaxf(fmaf(bs2f(b[k]), sc, sh), 0.f)
            + fmaxf(fmaf(bs2f(cc[k]), sc, sh), 0.f) + fmaxf(fmaf(bs2f(d[k]), sc, sh), 0.f);
    res.h[k] = f2b(v * 0.25f);
  }
  *(v8s*)(out + (img * 36 + pp) * 32 + c8 * 8) = res.v;
}

// ---------- conv3 apply: inline bnp3; pool + broadcast to 4 beams ----------
__global__ __launch_bounds__(256) void conv3_apply_k(
    const float* __restrict__ in, const float* __restrict__ Sacc3,
    const float* __restrict__ g, const float* __restrict__ bt,
    float* __restrict__ hs)
{
  int idx = blockIdx.x * 256 + threadIdx.x;  // exactly 2048*128
  int img = idx >> 7, r = idx & 127;
  int c = r >> 2, q = r & 3;
  int py = q >> 1, px = q & 1;
  int p0 = py * 8 + px * 2;
  const float* bp = in + img * 512 + c;
  const float invn = 1.f / (2048.f * 16.f);
  float s = Sacc3[2 * c], ssum = Sacc3[2 * c + 1];
  float mean = s * invn;
  float var = ssum * invn - mean * mean;
  float sc = g[c] / sqrtf(var + EPSV);
  float sh = bt[c] - mean * sc;
  float v = (fmaxf(fmaf(bp[p0 * 32], sc, sh), 0.f)
           + fmaxf(fmaf(bp[(p0 + 1) * 32], sc, sh), 0.f)
           + fmaxf(fmaf(bp[(p0 + 4) * 32], sc, sh), 0.f)
           + fmaxf(fmaf(bp[(p0 + 5) * 32], sc, sh), 0.f)) * 0.25f;
  float* hb = hs + img * 512 + r;
  hb[0] = v; hb[128] = v; hb[256] = v; hb[384] = v;
}

// ---------- fused MoE 3 steps + head, state in wave-private LDS ----------
__global__ __launch_bounds__(256) void moe_fused_k(
    const float* __restrict__ hs, const bf16* __restrict__ Web,
    const float* __restrict__ be, const bf16* __restrict__ Wob,
    const float* __restrict__ bo, const float* __restrict__ sv,
    const int* __restrict__ cnt27, const int* __restrict__ lists,
    float* __restrict__ out)
{
  int t = threadIdx.x, lane = t & 63, wv = t >> 6;
  int m = lane & 15, kg = lane >> 4;
  __shared__ float st[4][16][132];

  int g = blockIdx.x * 4 + wv;
  int sig = -1, tile = 0, cntS = 0, base = 0;
  for (int s = 0; s < 64; ++s) {
    int c = cnt27[s], nt = (c + 15) >> 4;
    if (g >= base && g < base + nt) { sig = s; tile = g - base; cntS = c; }
    base += nt;
  }
  if (sig < 0) return;
  const int* lp = lists + sig * 8192;
  int ra = tile * 16 + m;
  int rowA = lp[ra < cntS ? ra : cntS - 1];

  const float* hrow = hs + rowA * 128 + kg * 32;
#pragma unroll
  for (int q = 0; q < 8; ++q)
    *(float4*)&st[wv][m][kg * 32 + q * 4] = ((const float4*)hrow)[q];

  int es[3] = { sig & 3, (sig >> 2) & 3, sig >> 4 };
#pragma unroll
  for (int stp = 0; stp < 3; ++stp) {
    int e = es[stp];
    if (e == 3) continue;
    const short* wbs = (const short*)(Web + e * 16384);
    v8s afr[4];
#pragma unroll
    for (int kk = 0; kk < 4; ++kk) {
      float4 a0 = *(const float4*)&st[wv][m][kk * 32 + kg * 8];
      float4 a1 = *(const float4*)&st[wv][m][kk * 32 + kg * 8 + 4];
      afr[kk][0] = f2bs(a0.x); afr[kk][1] = f2bs(a0.y);
      afr[kk][2] = f2bs(a0.z); afr[kk][3] = f2bs(a0.w);
      afr[kk][4] = f2bs(a1.x); afr[kk][5] = f2bs(a1.y);
      afr[kk][6] = f2bs(a1.z); afr[kk][7] = f2bs(a1.w);
    }
#pragma unroll
    for (int ob = 0; ob < 8; ++ob) {
      v4f acc = {0.f, 0.f, 0.f, 0.f};
#pragma unroll
      for (int kk = 0; kk < 4; ++kk) {
        v8s bfr;
#pragma unroll
        for (int j = 0; j < 8; ++j)
          bfr[j] = wbs[(kk * 32 + kg * 8 + j) * 128 + ob * 16 + m];
        acc = __builtin_amdgcn_mfma_f32_16x16x32_bf16(afr[kk], bfr, acc, 0, 0, 0);
      }
      float bb = be[e * 128 + ob * 16 + m];
#pragma unroll
      for (int j = 0; j < 4; ++j)
        st[wv][kg * 4 + j][ob * 16 + m] = fmaxf(acc[j] + bb, 0.f);
    }
  }

  float ps = 1.f;
#pragma unroll
  for (int i = 0; i < 12; ++i) ps *= sv[i];
  const short* wos = (const short*)Wob;
  v8s afr[4];
#pragma unroll
  for (int kk = 0; kk < 4; ++kk) {
    float4 a0 = *(const float4*)&st[wv][m][kk * 32 + kg * 8];
    float4 a1 = *(const float4*)&st[wv][m][kk * 32 + kg * 8 + 4];
    afr[kk][0] = f2bs(a0.x); afr[kk][1] = f2bs(a0.y);
    afr[kk][2] = f2bs(a0.z); afr[kk][3] = f2bs(a0.w);
    afr[kk][4] = f2bs(a1.x); afr[kk][5] = f2bs(a1.y);
    afr[kk][6] = f2bs(a1.z); afr[kk][7] = f2bs(a1.w);
  }
  v4f acc = {0.f, 0.f, 0.f, 0.f};
#pragma unroll
  for (int kk = 0; kk < 4; ++kk) {
    v8s bfr;
#pragma unroll
    for (int j = 0; j < 8; ++j)
      bfr[j] = wos[(kk * 32 + kg * 8 + j) * 16 + m];
    acc = __builtin_amdgcn_mfma_f32_16x16x32_bf16(afr[kk], bfr, acc, 0, 0, 0);
  }
  if (m < 10) {
    float bov = bo[m];
#pragma unroll
    for (int j = 0; j < 4; ++j) {
      int idx = tile * 16 + kg * 4 + j;
      if (idx < cntS) out[lp[idx] * 10 + m] = (acc[j] + bov) * ps;
    }
  }
}

extern "C" void kernel_launch(void* const* d_in, const int* in_sizes, int n_in,
                              void* d_out, int out_size, void* d_ws, size_t ws_size,
                              hipStream_t stream)
{
  float* out = (float*)d_out;

  static const int EXP[19] = {2097152, 98304, 12, 288, 32, 9216, 32, 9216, 32,
                              32, 32, 32, 32, 32, 32, 49152, 384, 1280, 10};
  int bad = -1;
  if (n_in != 19) bad = 100;
  else
    for (int i = 0; i < 19; ++i)
      if (in_sizes[i] != EXP[i]) { bad = i; break; }
  if (bad >= 0) {
    fill_k<<<(out_size + 255) / 256, 256, 0, stream>>>(out, 1000.f + 10.f * bad, out_size);
    return;
  }
  const size_t NEED = 75764992;
  if (ws_size < NEED) {
    fill_k<<<(out_size + 255) / 256, 256, 0, stream>>>(
        out, 3000.f + (float)(ws_size >> 20), out_size);
    return;
  }

  const float* x    = (const float*)d_in[0];
  const float* traj = (const float*)d_in[1];
  const float* sv   = (const float*)d_in[2];
  const float* c1w  = (const float*)d_in[3];
  const float* c1b  = (const float*)d_in[4];
  const float* c2w  = (const float*)d_in[5];
  const float* c3w  = (const float*)d_in[7];
  const float* g1   = (const float*)d_in[9];
  const float* bt1  = (const float*)d_in[10];
  const float* g2   = (const float*)d_in[11];
  const float* bt2  = (const float*)d_in[12];
  const float* g3   = (const float*)d_in[13];
  const float* bt3  = (const float*)d_in[14];
  const float* We   = (const float*)d_in[15];
  const float* be   = (const float*)d_in[16];
  const float* Wo   = (const float*)d_in[17];
  const float* bo   = (const float*)d_in[18];

  char* w = (char*)d_ws;
  bf16*  pooled1  = (bf16*)(w + 0);          // NHWC bf16, 29,491,200 B
  bf16*  conv2out = (bf16*)(w + 29491200);   // NHWC bf16, 22,151,168 B
  bf16*  pooled2  = (bf16*)(w + 51642368);   // NHWC bf16, 4,718,592 B
  bf16*  Web      = (bf16*)(w + 56360960);   // 98,304 B
  float* conv3out = (float*)(w + 61079552);  // NHWC f32, 4,194,304 B
  float* hsA      = (float*)(w + 65273856);  // 4,194,304 B
  float* hsB      = (float*)(w + 69468160);  // weight staging only
  float* Macc     = (float*)(w + 73662464);  // 64 f32 (54 used)
  float* Sacc2    = (float*)(w + 73662720);  // 64 f32
  float* Sacc3    = (float*)(w + 73662976);  // 64 f32
  int*   cnt27    = (int*)(w + 73663488);    // 256 B
  bf16*  Wob      = (bf16*)(w + 73663744);   // 4,096 B
  int*   lists    = (int*)(w + 73667840);    // 64*8192*4 = 2,097,152 -> end 75,764,992
  bf16*  w2b      = (bf16*)hsB;
  bf16*  w3b      = w2b + 9216;

  setup_k<<<272, 256, 0, stream>>>(c2w, c3w, We, Wo, w2b, w3b, Web, Wob,
                                   cnt27, Macc, Sacc2, Sacc3);
  front_k<<<544, 256, 0, stream>>>(traj, x, cnt27, lists, Macc);
  conv1_apply_k<<<2048, 256, 0, stream>>>(x, c1w, c1b, g1, bt1, Macc, pooled1);
  conv_mfma_k<15, 13, 169, true><<<1024, 256, 0, stream>>>(pooled1, w2b, conv2out,
                                                           Sacc2, 21632);
  conv2_apply_k<<<1152, 256, 0, stream>>>(conv2out, Sacc2, g2, bt2, pooled2);
  conv_mfma_k<6, 4, 16, false><<<256, 256, 0, stream>>>(pooled2, w3b, conv3out,
                                                        Sacc3, 2048);
  conv3_apply_k<<<1024, 256, 0, stream>>>(conv3out, Sacc3, g3, bt3, hsA);
  moe_fused_k<<<256, 256, 0, stream>>>(hsA, Web, be, Wob, bo, sv, cnt27, lists, out);
}